// Round 1
// baseline (173.683 us; speedup 1.0000x reference)
//
#include <hip/hip_runtime.h>
#include <hip/hip_cooperative_groups.h>

namespace cg = cooperative_groups;

// B=8, M=12, N=32, D=256, C=1024, O=512, BM=96 (b*m rows).
//
// Single cooperative kernel, grid 192 x 256 (1 block/CU, co-resident).
// Phases (2 grid syncs instead of 4 kernel launches):
//   P1: block-local Ssum + ef synth + GEMM1 + relu -> Ht[96][512]   (bid = bmG*16 + oT)
//   grid.sync()
//   P2: GEMM2 + sigmoid -> Et[96][1024]                             (bid = bmG*16 + cQ)
//   grid.sync()
//   P3: stage x, LDS Ssum, gram, mask, softmax, att@x -> out        (bid = bm*2 + half)
//
// ws: Ht at +0 (49152 f), Et at +49152 (98304 f) = 576 KB.

__device__ __forceinline__ float dot4(float4 a, float4 b) {
    return a.x*b.x + a.y*b.y + a.z*b.z + a.w*b.w;
}
__device__ __forceinline__ void fma4(float4& acc, float s, float4 v) {
    acc.x += s*v.x; acc.y += s*v.y; acc.z += s*v.z; acc.w += s*v.w;
}

union SMem {
    struct { float S[8][32]; float ef[8][1024]; } p1;                   // 33 KB
    struct { float hl[8][512]; } p2;                                    // 16 KB
    struct { float4 xs4[32][65]; float att[32][36]; float S[32]; } p3;  // ~37 KB
};

__global__ __launch_bounds__(256) void fused(
        const float* __restrict__ x, const float* __restrict__ W1,
        const float* __restrict__ W2, float* __restrict__ out,
        float* __restrict__ Ht, float* __restrict__ Et)
{
    cg::grid_group grid = cg::this_grid();
    __shared__ SMem sm;
    const int t = threadIdx.x;
    const int bid = blockIdx.x;
    const float4* x4 = (const float4*)x;

    // ---------------- P1: Ssum(local) + ef + GEMM1 + relu ----------------
    {
        const int bmG = bid >> 4, oT = bid & 15;
        // local row sums for the 8 bm rows of this group (kS pattern, looped)
        {
            const int n = t >> 3, dq = t & 7;
            #pragma unroll
            for (int bl = 0; bl < 8; ++bl) {
                const float4* xb = x4 + (bmG*8 + bl)*2048;
                float s = 0.f;
                #pragma unroll
                for (int j = 0; j < 8; ++j) {
                    float4 v = xb[n*64 + dq + 8*j];
                    s += v.x + v.y + v.z + v.w;
                }
                s += __shfl_xor(s, 1, 8);
                s += __shfl_xor(s, 2, 8);
                s += __shfl_xor(s, 4, 8);
                if (dq == 0) sm.p1.S[bl][n] = s;
            }
        }
        __syncthreads();
        // ef[c=n*32+k] = (S_n + 2*S_k - (n==k)*S_k) / 512
        #pragma unroll
        for (int i = 0; i < 32; ++i) {
            int idx = t + 256*i;
            int bl = idx >> 10, c = idx & 1023;
            int nn = c >> 5, kk = c & 31;
            float sn = sm.p1.S[bl][nn], sk = sm.p1.S[bl][kk];
            sm.p1.ef[bl][c] = (sn + 2.f*sk - (nn == kk ? sk : 0.f)) * (1.f/512.f);
        }
        __syncthreads();
        // GEMM1: 32 o's per block (2 per thread), ef fragment reused across both
        const int clane = t & 15, og = t >> 4;
        const int o0 = oT*32 + og;
        const float4* w40 = (const float4*)(W1 + o0*1024);
        const float4* w41 = (const float4*)(W1 + (o0+16)*1024);
        float acc0[8] = {0.f,0.f,0.f,0.f,0.f,0.f,0.f,0.f};
        float acc1[8] = {0.f,0.f,0.f,0.f,0.f,0.f,0.f,0.f};
        #pragma unroll
        for (int co = 0; co < 16; ++co) {
            float4 e[8];
            #pragma unroll
            for (int bl = 0; bl < 8; ++bl)
                e[bl] = *((const float4*)&sm.p1.ef[bl][(co*16 + clane)*4]);
            float4 wa = w40[co*16 + clane];
            float4 wb = w41[co*16 + clane];
            #pragma unroll
            for (int bl = 0; bl < 8; ++bl) {
                acc0[bl] += dot4(wa, e[bl]);
                acc1[bl] += dot4(wb, e[bl]);
            }
        }
        #pragma unroll
        for (int bl = 0; bl < 8; ++bl) {
            float a = acc0[bl], b = acc1[bl];
            a += __shfl_xor(a, 1, 16); b += __shfl_xor(b, 1, 16);
            a += __shfl_xor(a, 2, 16); b += __shfl_xor(b, 2, 16);
            a += __shfl_xor(a, 4, 16); b += __shfl_xor(b, 4, 16);
            a += __shfl_xor(a, 8, 16); b += __shfl_xor(b, 8, 16);
            acc0[bl] = a; acc1[bl] = b;
        }
        if (clane == 0) {
            #pragma unroll
            for (int bl = 0; bl < 8; ++bl) {
                int row = (bmG*8 + bl)*512;
                Ht[row + o0]      = fmaxf(acc0[bl], 0.f);
                Ht[row + o0 + 16] = fmaxf(acc1[bl], 0.f);
            }
        }
    }
    __threadfence();
    grid.sync();

    // ---------------- P2: GEMM2 + sigmoid ----------------
    {
        const int bmG = bid >> 4, cQ = bid & 15;
        const float4* Ht4 = (const float4*)Ht;
        #pragma unroll
        for (int i = 0; i < 4; ++i) {
            int idx = t + 256*i;              // 1024 = 8 bm x 128 f4
            int bl = idx >> 7, o4 = idx & 127;
            *((float4*)&sm.p2.hl[bl][o4*4]) = Ht4[(bmG*8 + bl)*128 + o4];
        }
        __syncthreads();
        const int olane = t & 15, cgp = t >> 4;
        const int c0 = cQ*64 + cgp;           // 64 c's per block, 4 per thread
        const float4* w4a = (const float4*)(W2 + (c0     )*512);
        const float4* w4b = (const float4*)(W2 + (c0 + 16)*512);
        const float4* w4c = (const float4*)(W2 + (c0 + 32)*512);
        const float4* w4d = (const float4*)(W2 + (c0 + 48)*512);
        float accA[8] = {0.f,0.f,0.f,0.f,0.f,0.f,0.f,0.f};
        float accB[8] = {0.f,0.f,0.f,0.f,0.f,0.f,0.f,0.f};
        float accC[8] = {0.f,0.f,0.f,0.f,0.f,0.f,0.f,0.f};
        float accD[8] = {0.f,0.f,0.f,0.f,0.f,0.f,0.f,0.f};
        #pragma unroll
        for (int oo = 0; oo < 8; ++oo) {
            float4 hv[8];
            #pragma unroll
            for (int bl = 0; bl < 8; ++bl)
                hv[bl] = *((const float4*)&sm.p2.hl[bl][(oo*16 + olane)*4]);
            float4 wa = w4a[oo*16 + olane];
            float4 wb = w4b[oo*16 + olane];
            float4 wc = w4c[oo*16 + olane];
            float4 wd = w4d[oo*16 + olane];
            #pragma unroll
            for (int bl = 0; bl < 8; ++bl) {
                accA[bl] += dot4(wa, hv[bl]);
                accB[bl] += dot4(wb, hv[bl]);
                accC[bl] += dot4(wc, hv[bl]);
                accD[bl] += dot4(wd, hv[bl]);
            }
        }
        #pragma unroll
        for (int bl = 0; bl < 8; ++bl) {
            float a = accA[bl], b = accB[bl], c = accC[bl], d = accD[bl];
            #pragma unroll
            for (int m = 1; m < 16; m <<= 1) {
                a += __shfl_xor(a, m, 16);
                b += __shfl_xor(b, m, 16);
                c += __shfl_xor(c, m, 16);
                d += __shfl_xor(d, m, 16);
            }
            accA[bl]=a; accB[bl]=b; accC[bl]=c; accD[bl]=d;
        }
        if (olane == 0) {
            #pragma unroll
            for (int bl = 0; bl < 8; ++bl) {
                int row = (bmG*8 + bl)*1024;
                Et[row + c0]      = 1.f/(1.f + __expf(-accA[bl]));
                Et[row + c0 + 16] = 1.f/(1.f + __expf(-accB[bl]));
                Et[row + c0 + 32] = 1.f/(1.f + __expf(-accC[bl]));
                Et[row + c0 + 48] = 1.f/(1.f + __expf(-accD[bl]));
            }
        }
    }
    __threadfence();
    grid.sync();

    // ---------------- P3: gram + mask + softmax + att@x ----------------
    {
        const int bm = bid >> 1, hh = bid & 1;
        #pragma unroll
        for (int i = 0; i < 8; ++i) {
            int idx = t + 256*i;              // 0..2047
            sm.p3.xs4[idx >> 6][idx & 63] = x4[bm*2048 + idx];
        }
        __syncthreads();
        // Ssum from staged tile (kS pattern on LDS)
        {
            int r = t >> 3, dq = t & 7;
            float s = 0.f;
            #pragma unroll
            for (int j = 0; j < 8; ++j) {
                float4 v = sm.p3.xs4[r][dq + 8*j];
                s += v.x + v.y + v.z + v.w;
            }
            s += __shfl_xor(s, 1, 8);
            s += __shfl_xor(s, 2, 8);
            s += __shfl_xor(s, 4, 8);
            if (dq == 0) sm.p3.S[r] = s;
        }
        __syncthreads();
        // Gram 2x2 register tile + mask -> logits
        {
            int a = t >> 4, b = t & 15;
            float g00=0.f, g01=0.f, g10=0.f, g11=0.f;
            #pragma unroll 8
            for (int q = 0; q < 64; ++q) {
                float4 a0 = sm.p3.xs4[a][q],    a1 = sm.p3.xs4[a+16][q];
                float4 b0 = sm.p3.xs4[b][q],    b1 = sm.p3.xs4[b+16][q];
                g00 += dot4(a0,b0); g01 += dot4(a0,b1);
                g10 += dot4(a1,b0); g11 += dot4(a1,b1);
            }
            float sa0 = sm.p3.S[a]    * (1.f/256.f);
            float sa1 = sm.p3.S[a+16] * (1.f/256.f);
            float sb0 = sm.p3.S[b], sb1 = sm.p3.S[b+16];
            const float* Eb = Et + bm*1024;
            float e00 = Eb[a*32 + b];
            float e01 = Eb[a*32 + b+16];
            float e10 = Eb[(a+16)*32 + b];
            float e11 = Eb[(a+16)*32 + b+16];
            sm.p3.att[a][b]       = (g00 - sa0*sb0) > 0.f ? e00 : -1e12f;
            sm.p3.att[a][b+16]    = (g01 - sa0*sb1) > 0.f ? e01 : -1e12f;
            sm.p3.att[a+16][b]    = (g10 - sa1*sb0) > 0.f ? e10 : -1e12f;
            sm.p3.att[a+16][b+16] = (g11 - sa1*sb1) > 0.f ? e11 : -1e12f;
        }
        __syncthreads();
        // masked softmax per row: 8 lanes x 4 cols each
        {
            int r = t >> 3, q = t & 7;
            float4 lg = *((const float4*)&sm.p3.att[r][q*4]);
            float m = fmaxf(fmaxf(lg.x,lg.y), fmaxf(lg.z,lg.w));
            m = fmaxf(m, __shfl_xor(m,1,8));
            m = fmaxf(m, __shfl_xor(m,2,8));
            m = fmaxf(m, __shfl_xor(m,4,8));
            float4 p;
            p.x = __expf(lg.x-m); p.y = __expf(lg.y-m);
            p.z = __expf(lg.z-m); p.w = __expf(lg.w-m);
            float s = p.x+p.y+p.z+p.w;
            s += __shfl_xor(s,1,8);
            s += __shfl_xor(s,2,8);
            s += __shfl_xor(s,4,8);
            float inv = 1.f/s;
            p.x*=inv; p.y*=inv; p.z*=inv; p.w*=inv;
            *((float4*)&sm.p3.att[r][q*4]) = p;
        }
        __syncthreads();
        // out[r, d-half] = sum_k att[r,k] * x[k, d-half]
        {
            int txl = t & 31, wy = t >> 5;
            int r0 = wy*4;
            float4 acc0={0,0,0,0}, acc1={0,0,0,0}, acc2={0,0,0,0}, acc3={0,0,0,0};
            #pragma unroll
            for (int kq = 0; kq < 8; ++kq) {
                float4 xa = sm.p3.xs4[kq*4+0][hh*32 + txl];
                float4 xb = sm.p3.xs4[kq*4+1][hh*32 + txl];
                float4 xc = sm.p3.xs4[kq*4+2][hh*32 + txl];
                float4 xd = sm.p3.xs4[kq*4+3][hh*32 + txl];
                float4 w0 = *((const float4*)&sm.p3.att[r0+0][kq*4]);
                float4 w1 = *((const float4*)&sm.p3.att[r0+1][kq*4]);
                float4 w2 = *((const float4*)&sm.p3.att[r0+2][kq*4]);
                float4 w3 = *((const float4*)&sm.p3.att[r0+3][kq*4]);
                fma4(acc0,w0.x,xa); fma4(acc0,w0.y,xb); fma4(acc0,w0.z,xc); fma4(acc0,w0.w,xd);
                fma4(acc1,w1.x,xa); fma4(acc1,w1.y,xb); fma4(acc1,w1.z,xc); fma4(acc1,w1.w,xd);
                fma4(acc2,w2.x,xa); fma4(acc2,w2.y,xb); fma4(acc2,w2.z,xc); fma4(acc2,w2.w,xd);
                fma4(acc3,w3.x,xa); fma4(acc3,w3.y,xb); fma4(acc3,w3.z,xc); fma4(acc3,w3.w,xd);
            }
            float4* out4 = (float4*)out;
            int base = bm*2048 + hh*32 + txl;
            out4[base + (r0+0)*64] = acc0;
            out4[base + (r0+1)*64] = acc1;
            out4[base + (r0+2)*64] = acc2;
            out4[base + (r0+3)*64] = acc3;
        }
    }
}

extern "C" void kernel_launch(void* const* d_in, const int* in_sizes, int n_in,
                              void* d_out, int out_size, void* d_ws, size_t ws_size,
                              hipStream_t stream) {
    const float* x  = (const float*)d_in[0];
    const float* W1 = (const float*)d_in[1];
    const float* W2 = (const float*)d_in[2];
    float* out = (float*)d_out;
    float* ws  = (float*)d_ws;

    float* Ht = ws;            // 49152 floats
    float* Et = ws + 49152;    // 98304 floats

    void* args[] = { (void*)&x, (void*)&W1, (void*)&W2,
                     (void*)&out, (void*)&Ht, (void*)&Et };
    hipLaunchCooperativeKernel((const void*)fused, dim3(192), dim3(256),
                               args, 0, stream);
}

// Round 2
// 119.280 us; speedup vs baseline: 1.4561x; 1.4561x over previous
//
#include <hip/hip_runtime.h>

// B=8, M=12, N=32, D=256, C=1024, O=512, BM=96 (b*m rows).
//
// Single NORMAL-launch kernel, grid 192 x 256 (capacity >= 4 blocks/CU at
// 38.4 KB LDS / 76 VGPR, so all 192 blocks are co-resident by construction).
// grid.sync() replaced by hand-rolled device-scope barriers (atomicAdd arrive
// + relaxed agent-scope spin + threadfence release/acquire). Barrier counters
// in ws, zeroed by hipMemsetAsync before the launch each iteration.
//
// Phases:
//   P1: block-local Ssum + ef synth + GEMM1 + relu -> Ht[96][512]   (bid = bmG*16 + oT)
//   bar0
//   P2: GEMM2 + sigmoid -> Et[96][1024]                             (bid = bmG*16 + cQ)
//   bar1
//   P3: stage x, LDS Ssum, gram, mask, softmax, att@x -> out        (bid = bm*2 + half)
//
// ws: Ht at +0 (49152 f), Et at +49152 (98304 f), barriers at +147456 (16 u32).

__device__ __forceinline__ float dot4(float4 a, float4 b) {
    return a.x*b.x + a.y*b.y + a.z*b.z + a.w*b.w;
}
__device__ __forceinline__ void fma4(float4& acc, float s, float4 v) {
    acc.x += s*v.x; acc.y += s*v.y; acc.z += s*v.z; acc.w += s*v.w;
}

// Device-scope grid barrier. ctr must be 0 before first use this launch.
__device__ __forceinline__ void gridbar(unsigned int* ctr, unsigned int nblk) {
    __syncthreads();                      // all waves' stores issued (vmcnt drained at barrier)
    if (threadIdx.x == 0) {
        __threadfence();                  // release: push this XCD's L2 out
        __hip_atomic_fetch_add(ctr, 1u, __ATOMIC_RELAXED, __HIP_MEMORY_SCOPE_AGENT);
        while (__hip_atomic_load(ctr, __ATOMIC_RELAXED, __HIP_MEMORY_SCOPE_AGENT) < nblk) {
            __builtin_amdgcn_s_sleep(2);
        }
        __threadfence();                  // acquire: invalidate stale L1/L2 lines
    }
    __syncthreads();
}

union SMem {
    struct { float S[8][32]; float ef[8][1024]; } p1;                   // 33 KB
    struct { float hl[8][512]; } p2;                                    // 16 KB
    struct { float4 xs4[32][65]; float att[32][36]; float S[32]; } p3;  // ~37 KB
};

__global__ __launch_bounds__(256) void fused(
        const float* __restrict__ x, const float* __restrict__ W1,
        const float* __restrict__ W2, float* __restrict__ out,
        float* __restrict__ Ht, float* __restrict__ Et,
        unsigned int* __restrict__ bar)
{
    __shared__ SMem sm;
    const int t = threadIdx.x;
    const int bid = blockIdx.x;
    const float4* x4 = (const float4*)x;

    // ---------------- P1: Ssum(local) + ef + GEMM1 + relu ----------------
    {
        const int bmG = bid >> 4, oT = bid & 15;
        // local row sums for the 8 bm rows of this group
        {
            const int n = t >> 3, dq = t & 7;
            #pragma unroll
            for (int bl = 0; bl < 8; ++bl) {
                const float4* xb = x4 + (bmG*8 + bl)*2048;
                float s = 0.f;
                #pragma unroll
                for (int j = 0; j < 8; ++j) {
                    float4 v = xb[n*64 + dq + 8*j];
                    s += v.x + v.y + v.z + v.w;
                }
                s += __shfl_xor(s, 1, 8);
                s += __shfl_xor(s, 2, 8);
                s += __shfl_xor(s, 4, 8);
                if (dq == 0) sm.p1.S[bl][n] = s;
            }
        }
        __syncthreads();
        // ef[c=n*32+k] = (S_n + 2*S_k - (n==k)*S_k) / 512
        #pragma unroll
        for (int i = 0; i < 32; ++i) {
            int idx = t + 256*i;
            int bl = idx >> 10, c = idx & 1023;
            int nn = c >> 5, kk = c & 31;
            float sn = sm.p1.S[bl][nn], sk = sm.p1.S[bl][kk];
            sm.p1.ef[bl][c] = (sn + 2.f*sk - (nn == kk ? sk : 0.f)) * (1.f/512.f);
        }
        __syncthreads();
        // GEMM1: 32 o's per block (2 per thread), ef fragment reused across both
        const int clane = t & 15, og = t >> 4;
        const int o0 = oT*32 + og;
        const float4* w40 = (const float4*)(W1 + o0*1024);
        const float4* w41 = (const float4*)(W1 + (o0+16)*1024);
        float acc0[8] = {0.f,0.f,0.f,0.f,0.f,0.f,0.f,0.f};
        float acc1[8] = {0.f,0.f,0.f,0.f,0.f,0.f,0.f,0.f};
        #pragma unroll
        for (int co = 0; co < 16; ++co) {
            float4 e[8];
            #pragma unroll
            for (int bl = 0; bl < 8; ++bl)
                e[bl] = *((const float4*)&sm.p1.ef[bl][(co*16 + clane)*4]);
            float4 wa = w40[co*16 + clane];
            float4 wb = w41[co*16 + clane];
            #pragma unroll
            for (int bl = 0; bl < 8; ++bl) {
                acc0[bl] += dot4(wa, e[bl]);
                acc1[bl] += dot4(wb, e[bl]);
            }
        }
        #pragma unroll
        for (int bl = 0; bl < 8; ++bl) {
            float a = acc0[bl], b = acc1[bl];
            a += __shfl_xor(a, 1, 16); b += __shfl_xor(b, 1, 16);
            a += __shfl_xor(a, 2, 16); b += __shfl_xor(b, 2, 16);
            a += __shfl_xor(a, 4, 16); b += __shfl_xor(b, 4, 16);
            a += __shfl_xor(a, 8, 16); b += __shfl_xor(b, 8, 16);
            acc0[bl] = a; acc1[bl] = b;
        }
        if (clane == 0) {
            #pragma unroll
            for (int bl = 0; bl < 8; ++bl) {
                int row = (bmG*8 + bl)*512;
                Ht[row + o0]      = fmaxf(acc0[bl], 0.f);
                Ht[row + o0 + 16] = fmaxf(acc1[bl], 0.f);
            }
        }
    }
    gridbar(bar + 0, 192u);

    // ---------------- P2: GEMM2 + sigmoid ----------------
    {
        const int bmG = bid >> 4, cQ = bid & 15;
        const float4* Ht4 = (const float4*)Ht;
        #pragma unroll
        for (int i = 0; i < 4; ++i) {
            int idx = t + 256*i;              // 1024 = 8 bm x 128 f4
            int bl = idx >> 7, o4 = idx & 127;
            *((float4*)&sm.p2.hl[bl][o4*4]) = Ht4[(bmG*8 + bl)*128 + o4];
        }
        __syncthreads();
        const int olane = t & 15, cgp = t >> 4;
        const int c0 = cQ*64 + cgp;           // 64 c's per block, 4 per thread
        const float4* w4a = (const float4*)(W2 + (c0     )*512);
        const float4* w4b = (const float4*)(W2 + (c0 + 16)*512);
        const float4* w4c = (const float4*)(W2 + (c0 + 32)*512);
        const float4* w4d = (const float4*)(W2 + (c0 + 48)*512);
        float accA[8] = {0.f,0.f,0.f,0.f,0.f,0.f,0.f,0.f};
        float accB[8] = {0.f,0.f,0.f,0.f,0.f,0.f,0.f,0.f};
        float accC[8] = {0.f,0.f,0.f,0.f,0.f,0.f,0.f,0.f};
        float accD[8] = {0.f,0.f,0.f,0.f,0.f,0.f,0.f,0.f};
        #pragma unroll
        for (int oo = 0; oo < 8; ++oo) {
            float4 hv[8];
            #pragma unroll
            for (int bl = 0; bl < 8; ++bl)
                hv[bl] = *((const float4*)&sm.p2.hl[bl][(oo*16 + olane)*4]);
            float4 wa = w4a[oo*16 + olane];
            float4 wb = w4b[oo*16 + olane];
            float4 wc = w4c[oo*16 + olane];
            float4 wd = w4d[oo*16 + olane];
            #pragma unroll
            for (int bl = 0; bl < 8; ++bl) {
                accA[bl] += dot4(wa, hv[bl]);
                accB[bl] += dot4(wb, hv[bl]);
                accC[bl] += dot4(wc, hv[bl]);
                accD[bl] += dot4(wd, hv[bl]);
            }
        }
        #pragma unroll
        for (int bl = 0; bl < 8; ++bl) {
            float a = accA[bl], b = accB[bl], c = accC[bl], d = accD[bl];
            #pragma unroll
            for (int m = 1; m < 16; m <<= 1) {
                a += __shfl_xor(a, m, 16);
                b += __shfl_xor(b, m, 16);
                c += __shfl_xor(c, m, 16);
                d += __shfl_xor(d, m, 16);
            }
            accA[bl]=a; accB[bl]=b; accC[bl]=c; accD[bl]=d;
        }
        if (olane == 0) {
            #pragma unroll
            for (int bl = 0; bl < 8; ++bl) {
                int row = (bmG*8 + bl)*1024;
                Et[row + c0]      = 1.f/(1.f + __expf(-accA[bl]));
                Et[row + c0 + 16] = 1.f/(1.f + __expf(-accB[bl]));
                Et[row + c0 + 32] = 1.f/(1.f + __expf(-accC[bl]));
                Et[row + c0 + 48] = 1.f/(1.f + __expf(-accD[bl]));
            }
        }
    }
    gridbar(bar + 8, 192u);

    // ---------------- P3: gram + mask + softmax + att@x ----------------
    {
        const int bm = bid >> 1, hh = bid & 1;
        #pragma unroll
        for (int i = 0; i < 8; ++i) {
            int idx = t + 256*i;              // 0..2047
            sm.p3.xs4[idx >> 6][idx & 63] = x4[bm*2048 + idx];
        }
        __syncthreads();
        // Ssum from staged tile
        {
            int r = t >> 3, dq = t & 7;
            float s = 0.f;
            #pragma unroll
            for (int j = 0; j < 8; ++j) {
                float4 v = sm.p3.xs4[r][dq + 8*j];
                s += v.x + v.y + v.z + v.w;
            }
            s += __shfl_xor(s, 1, 8);
            s += __shfl_xor(s, 2, 8);
            s += __shfl_xor(s, 4, 8);
            if (dq == 0) sm.p3.S[r] = s;
        }
        __syncthreads();
        // Gram 2x2 register tile + mask -> logits
        {
            int a = t >> 4, b = t & 15;
            float g00=0.f, g01=0.f, g10=0.f, g11=0.f;
            #pragma unroll 8
            for (int q = 0; q < 64; ++q) {
                float4 a0 = sm.p3.xs4[a][q],    a1 = sm.p3.xs4[a+16][q];
                float4 b0 = sm.p3.xs4[b][q],    b1 = sm.p3.xs4[b+16][q];
                g00 += dot4(a0,b0); g01 += dot4(a0,b1);
                g10 += dot4(a1,b0); g11 += dot4(a1,b1);
            }
            float sa0 = sm.p3.S[a]    * (1.f/256.f);
            float sa1 = sm.p3.S[a+16] * (1.f/256.f);
            float sb0 = sm.p3.S[b], sb1 = sm.p3.S[b+16];
            const float* Eb = Et + bm*1024;
            float e00 = Eb[a*32 + b];
            float e01 = Eb[a*32 + b+16];
            float e10 = Eb[(a+16)*32 + b];
            float e11 = Eb[(a+16)*32 + b+16];
            sm.p3.att[a][b]       = (g00 - sa0*sb0) > 0.f ? e00 : -1e12f;
            sm.p3.att[a][b+16]    = (g01 - sa0*sb1) > 0.f ? e01 : -1e12f;
            sm.p3.att[a+16][b]    = (g10 - sa1*sb0) > 0.f ? e10 : -1e12f;
            sm.p3.att[a+16][b+16] = (g11 - sa1*sb1) > 0.f ? e11 : -1e12f;
        }
        __syncthreads();
        // masked softmax per row: 8 lanes x 4 cols each
        {
            int r = t >> 3, q = t & 7;
            float4 lg = *((const float4*)&sm.p3.att[r][q*4]);
            float m = fmaxf(fmaxf(lg.x,lg.y), fmaxf(lg.z,lg.w));
            m = fmaxf(m, __shfl_xor(m,1,8));
            m = fmaxf(m, __shfl_xor(m,2,8));
            m = fmaxf(m, __shfl_xor(m,4,8));
            float4 p;
            p.x = __expf(lg.x-m); p.y = __expf(lg.y-m);
            p.z = __expf(lg.z-m); p.w = __expf(lg.w-m);
            float s = p.x+p.y+p.z+p.w;
            s += __shfl_xor(s,1,8);
            s += __shfl_xor(s,2,8);
            s += __shfl_xor(s,4,8);
            float inv = 1.f/s;
            p.x*=inv; p.y*=inv; p.z*=inv; p.w*=inv;
            *((float4*)&sm.p3.att[r][q*4]) = p;
        }
        __syncthreads();
        // out[r, d-half] = sum_k att[r,k] * x[k, d-half]
        {
            int txl = t & 31, wy = t >> 5;
            int r0 = wy*4;
            float4 acc0={0,0,0,0}, acc1={0,0,0,0}, acc2={0,0,0,0}, acc3={0,0,0,0};
            #pragma unroll
            for (int kq = 0; kq < 8; ++kq) {
                float4 xa = sm.p3.xs4[kq*4+0][hh*32 + txl];
                float4 xb = sm.p3.xs4[kq*4+1][hh*32 + txl];
                float4 xc = sm.p3.xs4[kq*4+2][hh*32 + txl];
                float4 xd = sm.p3.xs4[kq*4+3][hh*32 + txl];
                float4 w0 = *((const float4*)&sm.p3.att[r0+0][kq*4]);
                float4 w1 = *((const float4*)&sm.p3.att[r0+1][kq*4]);
                float4 w2 = *((const float4*)&sm.p3.att[r0+2][kq*4]);
                float4 w3 = *((const float4*)&sm.p3.att[r0+3][kq*4]);
                fma4(acc0,w0.x,xa); fma4(acc0,w0.y,xb); fma4(acc0,w0.z,xc); fma4(acc0,w0.w,xd);
                fma4(acc1,w1.x,xa); fma4(acc1,w1.y,xb); fma4(acc1,w1.z,xc); fma4(acc1,w1.w,xd);
                fma4(acc2,w2.x,xa); fma4(acc2,w2.y,xb); fma4(acc2,w2.z,xc); fma4(acc2,w2.w,xd);
                fma4(acc3,w3.x,xa); fma4(acc3,w3.y,xb); fma4(acc3,w3.z,xc); fma4(acc3,w3.w,xd);
            }
            float4* out4 = (float4*)out;
            int base = bm*2048 + hh*32 + txl;
            out4[base + (r0+0)*64] = acc0;
            out4[base + (r0+1)*64] = acc1;
            out4[base + (r0+2)*64] = acc2;
            out4[base + (r0+3)*64] = acc3;
        }
    }
}

extern "C" void kernel_launch(void* const* d_in, const int* in_sizes, int n_in,
                              void* d_out, int out_size, void* d_ws, size_t ws_size,
                              hipStream_t stream) {
    const float* x  = (const float*)d_in[0];
    const float* W1 = (const float*)d_in[1];
    const float* W2 = (const float*)d_in[2];
    float* out = (float*)d_out;
    float* ws  = (float*)d_ws;

    float* Ht = ws;            // 49152 floats
    float* Et = ws + 49152;    // 98304 floats
    unsigned int* bar = (unsigned int*)(ws + 147456);   // 16 u32, 64 B

    hipMemsetAsync(bar, 0, 64, stream);   // ws is poisoned each iteration
    fused<<<192, 256, 0, stream>>>(x, W1, W2, out, Ht, Et, bar);
}

// Round 3
// 89.706 us; speedup vs baseline: 1.9361x; 1.3297x over previous
//
#include <hip/hip_runtime.h>

// B=8, M=12, N=32, D=256, C=1024, O=512, BM=96 (b*m rows).
//
// Single normal-launch kernel, grid 192 x 256 (1 block/CU; co-residency by
// capacity: 49 KB LDS, ~90 VGPR -> >=2 blocks/CU possible, 192 < 256 CUs).
//
// Cross-block sync: per-GROUP (16 blocks sharing bmG = bid>>4) arrive/spin
// barriers. NO __threadfence / L2 flush anywhere: all cross-block data
// (Ht, Et) moves via relaxed AGENT-scope atomic loads/stores (sc1 path,
// coherent at Infinity Cache across XCDs). __syncthreads() before the
// arrive-atomic drains vmcnt, so data stores are complete at the coherence
// point before the flag increments. Consumers' sc1 loads can't hit stale L2.
//
// Barrier counters live in zero-initialized __device__ globals (ws is
// poisoned each iteration). The last-of-16 block to finish resets its
// group's counters for the next launch (provably nobody still spins then).
//
// Schedule (both barriers latency-hidden):
//   P1: local Ssum + ef + GEMM1 + relu -> Ht           (bid = g*16 + oT)
//   arrive bar0
//   P3a: stage x tile + Ssum from LDS                  (hides bar0)
//   wait bar0
//   P2: GEMM2 + sigmoid -> Et                          (bid = g*16 + cQ)
//   arrive bar1
//   P3b: gram -> regs                                  (hides bar1)
//   wait bar1
//   P3c: mask(Et) + softmax + att@x -> out             (bid = bm*2 + half)

#define NGRP 12

__device__ unsigned int g_bar0[NGRP * 32];   // 128 B apart per group
__device__ unsigned int g_bar1[NGRP * 32];
__device__ unsigned int g_done[NGRP * 32];

__device__ __forceinline__ float dot4(float4 a, float4 b) {
    return a.x*b.x + a.y*b.y + a.z*b.z + a.w*b.w;
}
__device__ __forceinline__ void fma4(float4& acc, float s, float4 v) {
    acc.x += s*v.x; acc.y += s*v.y; acc.z += s*v.z; acc.w += s*v.w;
}

__device__ __forceinline__ void st_agent(float* p, float v) {
    __hip_atomic_store(p, v, __ATOMIC_RELAXED, __HIP_MEMORY_SCOPE_AGENT);
}
__device__ __forceinline__ float ld_agent(const float* p) {
    return __hip_atomic_load(p, __ATOMIC_RELAXED, __HIP_MEMORY_SCOPE_AGENT);
}
__device__ __forceinline__ unsigned long long ld_agent64(const unsigned long long* p) {
    return __hip_atomic_load(p, __ATOMIC_RELAXED, __HIP_MEMORY_SCOPE_AGENT);
}

// arrive: all block stores drained (syncthreads => vmcnt 0), then +1.
__device__ __forceinline__ void bar_arrive(unsigned int* ctr) {
    __syncthreads();
    if (threadIdx.x == 0)
        __hip_atomic_fetch_add(ctr, 1u, __ATOMIC_RELAXED, __HIP_MEMORY_SCOPE_AGENT);
}
__device__ __forceinline__ void bar_wait(unsigned int* ctr) {
    if (threadIdx.x == 0) {
        while (__hip_atomic_load(ctr, __ATOMIC_RELAXED, __HIP_MEMORY_SCOPE_AGENT) < 16u)
            __builtin_amdgcn_s_sleep(2);
    }
    __syncthreads();
}

union RegionA {
    struct { float S[8][32]; float ef[8][1024]; } p1;     // 33792 B
    struct { float4 xs4[32][65]; float S[32]; } p3;       // 33408 B
};
union RegionB {
    float hl[8][512];                                     // 16384 B
    float att[32][36];                                    //  4608 B
};

__global__ __launch_bounds__(256) void fused(
        const float* __restrict__ x, const float* __restrict__ W1,
        const float* __restrict__ W2, float* __restrict__ out,
        float* __restrict__ Ht, float* __restrict__ Et)
{
    __shared__ RegionA A;
    __shared__ RegionB Bm;
    const int t = threadIdx.x;
    const int bid = blockIdx.x;
    const int g = bid >> 4;          // bm-group 0..11
    const int gi = g * 32;
    const float4* x4 = (const float4*)x;

    // ---------------- P1: Ssum(local) + ef + GEMM1 + relu ----------------
    {
        const int oT = bid & 15;
        {
            const int n = t >> 3, dq = t & 7;
            #pragma unroll
            for (int bl = 0; bl < 8; ++bl) {
                const float4* xb = x4 + (g*8 + bl)*2048;
                float s = 0.f;
                #pragma unroll
                for (int j = 0; j < 8; ++j) {
                    float4 v = xb[n*64 + dq + 8*j];
                    s += v.x + v.y + v.z + v.w;
                }
                s += __shfl_xor(s, 1, 8);
                s += __shfl_xor(s, 2, 8);
                s += __shfl_xor(s, 4, 8);
                if (dq == 0) A.p1.S[bl][n] = s;
            }
        }
        __syncthreads();
        // ef[c=n*32+k] = (S_n + 2*S_k - (n==k)*S_k) / 512
        #pragma unroll
        for (int i = 0; i < 32; ++i) {
            int idx = t + 256*i;
            int bl = idx >> 10, c = idx & 1023;
            int nn = c >> 5, kk = c & 31;
            float sn = A.p1.S[bl][nn], sk = A.p1.S[bl][kk];
            A.p1.ef[bl][c] = (sn + 2.f*sk - (nn == kk ? sk : 0.f)) * (1.f/512.f);
        }
        __syncthreads();
        // GEMM1: 32 o's per block (2 per thread)
        const int clane = t & 15, og = t >> 4;
        const int o0 = oT*32 + og;
        const float4* w40 = (const float4*)(W1 + o0*1024);
        const float4* w41 = (const float4*)(W1 + (o0+16)*1024);
        float acc0[8] = {0.f,0.f,0.f,0.f,0.f,0.f,0.f,0.f};
        float acc1[8] = {0.f,0.f,0.f,0.f,0.f,0.f,0.f,0.f};
        #pragma unroll
        for (int co = 0; co < 16; ++co) {
            float4 e[8];
            #pragma unroll
            for (int bl = 0; bl < 8; ++bl)
                e[bl] = *((const float4*)&A.p1.ef[bl][(co*16 + clane)*4]);
            float4 wa = w40[co*16 + clane];
            float4 wb = w41[co*16 + clane];
            #pragma unroll
            for (int bl = 0; bl < 8; ++bl) {
                acc0[bl] += dot4(wa, e[bl]);
                acc1[bl] += dot4(wb, e[bl]);
            }
        }
        #pragma unroll
        for (int bl = 0; bl < 8; ++bl) {
            float a = acc0[bl], b = acc1[bl];
            a += __shfl_xor(a, 1, 16); b += __shfl_xor(b, 1, 16);
            a += __shfl_xor(a, 2, 16); b += __shfl_xor(b, 2, 16);
            a += __shfl_xor(a, 4, 16); b += __shfl_xor(b, 4, 16);
            a += __shfl_xor(a, 8, 16); b += __shfl_xor(b, 8, 16);
            acc0[bl] = a; acc1[bl] = b;
        }
        if (clane == 0) {
            #pragma unroll
            for (int bl = 0; bl < 8; ++bl) {
                int row = (g*8 + bl)*512;
                st_agent(&Ht[row + o0],      fmaxf(acc0[bl], 0.f));
                st_agent(&Ht[row + o0 + 16], fmaxf(acc1[bl], 0.f));
            }
        }
    }
    bar_arrive(&g_bar0[gi]);     // syncthreads inside: ef dead, Ht drained

    // ---------------- P3a: stage x tile + Ssum (hides bar0) ----------------
    const int bm = bid >> 1, hh = bid & 1;
    {
        #pragma unroll
        for (int i = 0; i < 8; ++i) {
            int idx = t + 256*i;              // 0..2047
            A.p3.xs4[idx >> 6][idx & 63] = x4[bm*2048 + idx];
        }
        __syncthreads();
        int r = t >> 3, dq = t & 7;
        float s = 0.f;
        #pragma unroll
        for (int j = 0; j < 8; ++j) {
            float4 v = A.p3.xs4[r][dq + 8*j];
            s += v.x + v.y + v.z + v.w;
        }
        s += __shfl_xor(s, 1, 8);
        s += __shfl_xor(s, 2, 8);
        s += __shfl_xor(s, 4, 8);
        if (dq == 0) A.p3.S[r] = s;
    }
    bar_wait(&g_bar0[gi]);       // syncthreads inside also publishes A.p3.S

    // ---------------- P2: GEMM2 + sigmoid ----------------
    {
        const int cQ = bid & 15;
        const unsigned long long* Ht8 =
            (const unsigned long long*)(Ht + (g*8)*512);
        #pragma unroll
        for (int j = 0; j < 8; ++j) {
            int pos = t + 256*j;              // 0..2047 u64 = 8 bm x 256
            unsigned long long v = ld_agent64(Ht8 + pos);
            int bl = pos >> 8, o2 = pos & 255;
            Bm.hl[bl][o2*2]   = __uint_as_float((unsigned)(v & 0xffffffffu));
            Bm.hl[bl][o2*2+1] = __uint_as_float((unsigned)(v >> 32));
        }
        __syncthreads();
        const int olane = t & 15, cgp = t >> 4;
        const int c0 = cQ*64 + cgp;           // 64 c's per block, 4 per thread
        const float4* w4a = (const float4*)(W2 + (c0     )*512);
        const float4* w4b = (const float4*)(W2 + (c0 + 16)*512);
        const float4* w4c = (const float4*)(W2 + (c0 + 32)*512);
        const float4* w4d = (const float4*)(W2 + (c0 + 48)*512);
        float accA[8] = {0.f,0.f,0.f,0.f,0.f,0.f,0.f,0.f};
        float accB[8] = {0.f,0.f,0.f,0.f,0.f,0.f,0.f,0.f};
        float accC[8] = {0.f,0.f,0.f,0.f,0.f,0.f,0.f,0.f};
        float accD[8] = {0.f,0.f,0.f,0.f,0.f,0.f,0.f,0.f};
        #pragma unroll
        for (int oo = 0; oo < 8; ++oo) {
            float4 hv[8];
            #pragma unroll
            for (int bl = 0; bl < 8; ++bl)
                hv[bl] = *((const float4*)&Bm.hl[bl][(oo*16 + olane)*4]);
            float4 wa = w4a[oo*16 + olane];
            float4 wb = w4b[oo*16 + olane];
            float4 wc = w4c[oo*16 + olane];
            float4 wd = w4d[oo*16 + olane];
            #pragma unroll
            for (int bl = 0; bl < 8; ++bl) {
                accA[bl] += dot4(wa, hv[bl]);
                accB[bl] += dot4(wb, hv[bl]);
                accC[bl] += dot4(wc, hv[bl]);
                accD[bl] += dot4(wd, hv[bl]);
            }
        }
        #pragma unroll
        for (int bl = 0; bl < 8; ++bl) {
            float a = accA[bl], b = accB[bl], c = accC[bl], d = accD[bl];
            #pragma unroll
            for (int m = 1; m < 16; m <<= 1) {
                a += __shfl_xor(a, m, 16);
                b += __shfl_xor(b, m, 16);
                c += __shfl_xor(c, m, 16);
                d += __shfl_xor(d, m, 16);
            }
            accA[bl]=a; accB[bl]=b; accC[bl]=c; accD[bl]=d;
        }
        if (olane == 0) {
            #pragma unroll
            for (int bl = 0; bl < 8; ++bl) {
                int row = (g*8 + bl)*1024;
                st_agent(&Et[row + c0],      1.f/(1.f + __expf(-accA[bl])));
                st_agent(&Et[row + c0 + 16], 1.f/(1.f + __expf(-accB[bl])));
                st_agent(&Et[row + c0 + 32], 1.f/(1.f + __expf(-accC[bl])));
                st_agent(&Et[row + c0 + 48], 1.f/(1.f + __expf(-accD[bl])));
            }
        }
    }
    bar_arrive(&g_bar1[gi]);     // syncthreads inside: hl dead, Et drained

    // ---------------- P3b: gram -> regs (hides bar1) ----------------
    const int ga = t >> 4, gb = t & 15;
    float g00=0.f, g01=0.f, g10=0.f, g11=0.f;
    {
        #pragma unroll 8
        for (int q = 0; q < 64; ++q) {
            float4 a0 = A.p3.xs4[ga][q],    a1 = A.p3.xs4[ga+16][q];
            float4 b0 = A.p3.xs4[gb][q],    b1 = A.p3.xs4[gb+16][q];
            g00 += dot4(a0,b0); g01 += dot4(a0,b1);
            g10 += dot4(a1,b0); g11 += dot4(a1,b1);
        }
    }
    float sa0 = A.p3.S[ga]    * (1.f/256.f);
    float sa1 = A.p3.S[ga+16] * (1.f/256.f);
    float sb0 = A.p3.S[gb], sb1 = A.p3.S[gb+16];
    bar_wait(&g_bar1[gi]);

    // ---------------- P3c: mask + softmax + att@x ----------------
    {
        const float* Eb = Et + bm*1024;
        float e00 = ld_agent(&Eb[ga*32 + gb]);
        float e01 = ld_agent(&Eb[ga*32 + gb+16]);
        float e10 = ld_agent(&Eb[(ga+16)*32 + gb]);
        float e11 = ld_agent(&Eb[(ga+16)*32 + gb+16]);
        Bm.att[ga][gb]       = (g00 - sa0*sb0) > 0.f ? e00 : -1e12f;
        Bm.att[ga][gb+16]    = (g01 - sa0*sb1) > 0.f ? e01 : -1e12f;
        Bm.att[ga+16][gb]    = (g10 - sa1*sb0) > 0.f ? e10 : -1e12f;
        Bm.att[ga+16][gb+16] = (g11 - sa1*sb1) > 0.f ? e11 : -1e12f;
    }
    __syncthreads();
    {
        int r = t >> 3, q = t & 7;
        float4 lg = *((const float4*)&Bm.att[r][q*4]);
        float m = fmaxf(fmaxf(lg.x,lg.y), fmaxf(lg.z,lg.w));
        m = fmaxf(m, __shfl_xor(m,1,8));
        m = fmaxf(m, __shfl_xor(m,2,8));
        m = fmaxf(m, __shfl_xor(m,4,8));
        float4 p;
        p.x = __expf(lg.x-m); p.y = __expf(lg.y-m);
        p.z = __expf(lg.z-m); p.w = __expf(lg.w-m);
        float s = p.x+p.y+p.z+p.w;
        s += __shfl_xor(s,1,8);
        s += __shfl_xor(s,2,8);
        s += __shfl_xor(s,4,8);
        float inv = 1.f/s;
        p.x*=inv; p.y*=inv; p.z*=inv; p.w*=inv;
        *((float4*)&Bm.att[r][q*4]) = p;
    }
    __syncthreads();
    {
        int txl = t & 31, wy = t >> 5;
        int r0 = wy*4;
        float4 acc0={0,0,0,0}, acc1={0,0,0,0}, acc2={0,0,0,0}, acc3={0,0,0,0};
        #pragma unroll
        for (int kq = 0; kq < 8; ++kq) {
            float4 xa = A.p3.xs4[kq*4+0][hh*32 + txl];
            float4 xb = A.p3.xs4[kq*4+1][hh*32 + txl];
            float4 xc = A.p3.xs4[kq*4+2][hh*32 + txl];
            float4 xd = A.p3.xs4[kq*4+3][hh*32 + txl];
            float4 w0 = *((const float4*)&Bm.att[r0+0][kq*4]);
            float4 w1 = *((const float4*)&Bm.att[r0+1][kq*4]);
            float4 w2 = *((const float4*)&Bm.att[r0+2][kq*4]);
            float4 w3 = *((const float4*)&Bm.att[r0+3][kq*4]);
            fma4(acc0,w0.x,xa); fma4(acc0,w0.y,xb); fma4(acc0,w0.z,xc); fma4(acc0,w0.w,xd);
            fma4(acc1,w1.x,xa); fma4(acc1,w1.y,xb); fma4(acc1,w1.z,xc); fma4(acc1,w1.w,xd);
            fma4(acc2,w2.x,xa); fma4(acc2,w2.y,xb); fma4(acc2,w2.z,xc); fma4(acc2,w2.w,xd);
            fma4(acc3,w3.x,xa); fma4(acc3,w3.y,xb); fma4(acc3,w3.z,xc); fma4(acc3,w3.w,xd);
        }
        float4* out4 = (float4*)out;
        int base = bm*2048 + hh*32 + txl;
        out4[base + (r0+0)*64] = acc0;
        out4[base + (r0+1)*64] = acc1;
        out4[base + (r0+2)*64] = acc2;
        out4[base + (r0+3)*64] = acc3;
    }

    // ---------------- self-reset of group counters for next launch --------
    // Every block reaching here has passed both barriers, so once all 16
    // have incremented g_done, nobody can still be spinning on bar0/bar1.
    if (t == 0) {
        unsigned int old = __hip_atomic_fetch_add(&g_done[gi], 1u,
                              __ATOMIC_RELAXED, __HIP_MEMORY_SCOPE_AGENT);
        if (old == 15u) {
            __hip_atomic_store(&g_bar0[gi], 0u, __ATOMIC_RELAXED, __HIP_MEMORY_SCOPE_AGENT);
            __hip_atomic_store(&g_bar1[gi], 0u, __ATOMIC_RELAXED, __HIP_MEMORY_SCOPE_AGENT);
            __hip_atomic_store(&g_done[gi], 0u, __ATOMIC_RELAXED, __HIP_MEMORY_SCOPE_AGENT);
        }
    }
}

extern "C" void kernel_launch(void* const* d_in, const int* in_sizes, int n_in,
                              void* d_out, int out_size, void* d_ws, size_t ws_size,
                              hipStream_t stream) {
    const float* x  = (const float*)d_in[0];
    const float* W1 = (const float*)d_in[1];
    const float* W2 = (const float*)d_in[2];
    float* out = (float*)d_out;
    float* ws  = (float*)d_ws;

    float* Ht = ws;            // 49152 floats
    float* Et = ws + 49152;    // 98304 floats

    fused<<<192, 256, 0, stream>>>(x, W1, W2, out, Ht, Et);
}

// Round 4
// 86.530 us; speedup vs baseline: 2.0072x; 1.0367x over previous
//
#include <hip/hip_runtime.h>

// B=8, M=12, N=32, D=256, C=1024, O=512, BM=96 (b*m rows).
//
// Single normal-launch kernel, grid 192 x 512 (8 waves/block = 2 waves/SIMD
// at 1 block/CU -- doubles latency hiding vs the 256-thread round-3 version,
// with thread tilings chosen so per-block LDS/global traffic is UNCHANGED).
//
// Cross-block sync: per-GROUP (16 blocks sharing g = bid>>4) arrive/spin
// barriers at agent scope; Ht/Et move via relaxed agent-scope atomics (sc1,
// coherent at IC across XCDs). No threadfence / L2 flush anywhere.
// Barrier counters in zero-initialized __device__ globals; last-of-16 block
// self-resets them for the next launch.
//
// Schedule (both barriers latency-hidden):
//   P1: local Ssum + ef + GEMM1 + relu -> Ht           (bid = g*16 + oT)
//   arrive bar0
//   P3a: stage x tile + Ssum from LDS                  (hides bar0)
//   wait bar0
//   P2: GEMM2 + sigmoid -> Et                          (bid = g*16 + cQ)
//   arrive bar1
//   P3b: gram partials + pair-combine -> regs          (hides bar1)
//   wait bar1
//   P3c: mask(Et) + softmax + att@x -> out             (bid = bm*2 + half)

#define NGRP 12

__device__ unsigned int g_bar0[NGRP * 32];   // 128 B apart per group
__device__ unsigned int g_bar1[NGRP * 32];
__device__ unsigned int g_done[NGRP * 32];

__device__ __forceinline__ float dot4(float4 a, float4 b) {
    return a.x*b.x + a.y*b.y + a.z*b.z + a.w*b.w;
}
__device__ __forceinline__ void fma4(float4& acc, float s, float4 v) {
    acc.x += s*v.x; acc.y += s*v.y; acc.z += s*v.z; acc.w += s*v.w;
}

__device__ __forceinline__ void st_agent(float* p, float v) {
    __hip_atomic_store(p, v, __ATOMIC_RELAXED, __HIP_MEMORY_SCOPE_AGENT);
}
__device__ __forceinline__ float ld_agent(const float* p) {
    return __hip_atomic_load(p, __ATOMIC_RELAXED, __HIP_MEMORY_SCOPE_AGENT);
}
__device__ __forceinline__ unsigned long long ld_agent64(const unsigned long long* p) {
    return __hip_atomic_load(p, __ATOMIC_RELAXED, __HIP_MEMORY_SCOPE_AGENT);
}

// arrive: all block stores drained (syncthreads => vmcnt 0), then +1.
__device__ __forceinline__ void bar_arrive(unsigned int* ctr) {
    __syncthreads();
    if (threadIdx.x == 0)
        __hip_atomic_fetch_add(ctr, 1u, __ATOMIC_RELAXED, __HIP_MEMORY_SCOPE_AGENT);
}
__device__ __forceinline__ void bar_wait(unsigned int* ctr) {
    if (threadIdx.x == 0) {
        while (__hip_atomic_load(ctr, __ATOMIC_RELAXED, __HIP_MEMORY_SCOPE_AGENT) < 16u)
            __builtin_amdgcn_s_sleep(2);
    }
    __syncthreads();
}

union RegionA {
    struct { float S[8][32]; float ef[8][1024]; } p1;     // 33792 B
    struct { float4 xs4[32][65]; float S[32]; } p3;       // 33408 B
};
union RegionB {
    float hl[8][512];                                     // 16384 B
    float att[32][36];                                    //  4608 B
};

__global__ __launch_bounds__(512) void fused(
        const float* __restrict__ x, const float* __restrict__ W1,
        const float* __restrict__ W2, float* __restrict__ out,
        float* __restrict__ Ht, float* __restrict__ Et)
{
    __shared__ RegionA A;
    __shared__ RegionB Bm;
    const int t = threadIdx.x;
    const int bid = blockIdx.x;
    const int g = bid >> 4;          // bm-group 0..11
    const int gi = g * 32;
    const float4* x4 = (const float4*)x;

    // ---------------- P1: Ssum(local) + ef + GEMM1 + relu ----------------
    {
        const int oT = bid & 15;
        {
            const int n = t >> 4, dq = t & 15;   // 32 rows x 16 lanes
            #pragma unroll
            for (int bl = 0; bl < 8; ++bl) {
                const float4* xb = x4 + (g*8 + bl)*2048;
                float s = 0.f;
                #pragma unroll
                for (int j = 0; j < 4; ++j) {
                    float4 v = xb[n*64 + dq + 16*j];
                    s += v.x + v.y + v.z + v.w;
                }
                s += __shfl_xor(s, 1, 16);
                s += __shfl_xor(s, 2, 16);
                s += __shfl_xor(s, 4, 16);
                s += __shfl_xor(s, 8, 16);
                if (dq == 0) A.p1.S[bl][n] = s;
            }
        }
        __syncthreads();
        // ef[c=n*32+k] = (S_n + 2*S_k - (n==k)*S_k) / 512
        #pragma unroll
        for (int i = 0; i < 16; ++i) {
            int idx = t + 512*i;
            int bl = idx >> 10, c = idx & 1023;
            int nn = c >> 5, kk = c & 31;
            float sn = A.p1.S[bl][nn], sk = A.p1.S[bl][kk];
            A.p1.ef[bl][c] = (sn + 2.f*sk - (nn == kk ? sk : 0.f)) * (1.f/512.f);
        }
        __syncthreads();
        // GEMM1: 32 o's per block, 2 per thread; 32-lane K slices (8 steps)
        const int clane = t & 31, og = t >> 5;   // og 0..15
        const int o0 = oT*32 + og;
        const float4* w40 = (const float4*)(W1 + o0*1024);
        const float4* w41 = (const float4*)(W1 + (o0+16)*1024);
        float acc0[8] = {0.f,0.f,0.f,0.f,0.f,0.f,0.f,0.f};
        float acc1[8] = {0.f,0.f,0.f,0.f,0.f,0.f,0.f,0.f};
        #pragma unroll
        for (int co = 0; co < 8; ++co) {
            float4 e[8];
            #pragma unroll
            for (int bl = 0; bl < 8; ++bl)
                e[bl] = *((const float4*)&A.p1.ef[bl][(co*32 + clane)*4]);
            float4 wa = w40[co*32 + clane];
            float4 wb = w41[co*32 + clane];
            #pragma unroll
            for (int bl = 0; bl < 8; ++bl) {
                acc0[bl] += dot4(wa, e[bl]);
                acc1[bl] += dot4(wb, e[bl]);
            }
        }
        #pragma unroll
        for (int bl = 0; bl < 8; ++bl) {
            float a = acc0[bl], b = acc1[bl];
            #pragma unroll
            for (int m = 1; m < 32; m <<= 1) {
                a += __shfl_xor(a, m, 32);
                b += __shfl_xor(b, m, 32);
            }
            acc0[bl] = a; acc1[bl] = b;
        }
        if (clane == 0) {
            #pragma unroll
            for (int bl = 0; bl < 8; ++bl) {
                int row = (g*8 + bl)*512;
                st_agent(&Ht[row + o0],      fmaxf(acc0[bl], 0.f));
                st_agent(&Ht[row + o0 + 16], fmaxf(acc1[bl], 0.f));
            }
        }
    }
    bar_arrive(&g_bar0[gi]);     // syncthreads inside: ef dead, Ht drained

    // ---------------- P3a: stage x tile + Ssum (hides bar0) ----------------
    const int bm = bid >> 1, hh = bid & 1;
    {
        #pragma unroll
        for (int i = 0; i < 4; ++i) {
            int idx = t + 512*i;              // 0..2047
            A.p3.xs4[idx >> 6][idx & 63] = x4[bm*2048 + idx];
        }
        __syncthreads();
        int r = t >> 4, dq = t & 15;
        float s = 0.f;
        #pragma unroll
        for (int j = 0; j < 4; ++j) {
            float4 v = A.p3.xs4[r][dq + 16*j];
            s += v.x + v.y + v.z + v.w;
        }
        s += __shfl_xor(s, 1, 16);
        s += __shfl_xor(s, 2, 16);
        s += __shfl_xor(s, 4, 16);
        s += __shfl_xor(s, 8, 16);
        if (dq == 0) A.p3.S[r] = s;
    }
    bar_wait(&g_bar0[gi]);       // syncthreads inside also publishes A.p3.S

    // ---------------- P2: GEMM2 + sigmoid ----------------
    {
        const int cQ = bid & 15;
        const unsigned long long* Ht8 =
            (const unsigned long long*)(Ht + (g*8)*512);
        #pragma unroll
        for (int j = 0; j < 4; ++j) {
            int pos = t + 512*j;              // 0..2047 u64 = 8 bm x 256
            unsigned long long v = ld_agent64(Ht8 + pos);
            int bl = pos >> 8, o2 = pos & 255;
            float2 f;
            f.x = __uint_as_float((unsigned)(v & 0xffffffffu));
            f.y = __uint_as_float((unsigned)(v >> 32));
            *((float2*)&Bm.hl[bl][o2*2]) = f;
        }
        __syncthreads();
        const int olane = t & 31, cgp = t >> 5;   // cgp 0..15
        const int c0 = cQ*64 + cgp;               // 4 c's per thread
        const float4* w4a = (const float4*)(W2 + (c0     )*512);
        const float4* w4b = (const float4*)(W2 + (c0 + 16)*512);
        const float4* w4c = (const float4*)(W2 + (c0 + 32)*512);
        const float4* w4d = (const float4*)(W2 + (c0 + 48)*512);
        float accA[8] = {0.f,0.f,0.f,0.f,0.f,0.f,0.f,0.f};
        float accB[8] = {0.f,0.f,0.f,0.f,0.f,0.f,0.f,0.f};
        float accC[8] = {0.f,0.f,0.f,0.f,0.f,0.f,0.f,0.f};
        float accD[8] = {0.f,0.f,0.f,0.f,0.f,0.f,0.f,0.f};
        #pragma unroll
        for (int oo = 0; oo < 4; ++oo) {
            float4 hv[8];
            #pragma unroll
            for (int bl = 0; bl < 8; ++bl)
                hv[bl] = *((const float4*)&Bm.hl[bl][(oo*32 + olane)*4]);
            float4 wa = w4a[oo*32 + olane];
            float4 wb = w4b[oo*32 + olane];
            float4 wc = w4c[oo*32 + olane];
            float4 wd = w4d[oo*32 + olane];
            #pragma unroll
            for (int bl = 0; bl < 8; ++bl) {
                accA[bl] += dot4(wa, hv[bl]);
                accB[bl] += dot4(wb, hv[bl]);
                accC[bl] += dot4(wc, hv[bl]);
                accD[bl] += dot4(wd, hv[bl]);
            }
        }
        #pragma unroll
        for (int bl = 0; bl < 8; ++bl) {
            float a = accA[bl], b = accB[bl], c = accC[bl], d = accD[bl];
            #pragma unroll
            for (int m = 1; m < 32; m <<= 1) {
                a += __shfl_xor(a, m, 32);
                b += __shfl_xor(b, m, 32);
                c += __shfl_xor(c, m, 32);
                d += __shfl_xor(d, m, 32);
            }
            accA[bl]=a; accB[bl]=b; accC[bl]=c; accD[bl]=d;
        }
        if (olane == 0) {
            #pragma unroll
            for (int bl = 0; bl < 8; ++bl) {
                int row = (g*8 + bl)*1024;
                st_agent(&Et[row + c0],      1.f/(1.f + __expf(-accA[bl])));
                st_agent(&Et[row + c0 + 16], 1.f/(1.f + __expf(-accB[bl])));
                st_agent(&Et[row + c0 + 32], 1.f/(1.f + __expf(-accC[bl])));
                st_agent(&Et[row + c0 + 48], 1.f/(1.f + __expf(-accD[bl])));
            }
        }
    }
    bar_arrive(&g_bar1[gi]);     // syncthreads inside: hl dead, Et drained

    // -------- P3b: gram partials (q split across lane pairs) + combine -----
    // thread = (pair p = t>>1, qh = t&1); pair tile rows (A,A+16)x(B,B+16).
    const int gp = t >> 1, qh = t & 1;
    const int ga = gp >> 4, gb = gp & 15;
    float g00=0.f, g01=0.f, g10=0.f, g11=0.f;
    {
        const int qbase = qh * 32;
        #pragma unroll 8
        for (int qq = 0; qq < 32; ++qq) {
            int q = qbase + qq;
            float4 a0 = A.p3.xs4[ga][q],    a1 = A.p3.xs4[ga+16][q];
            float4 b0 = A.p3.xs4[gb][q],    b1 = A.p3.xs4[gb+16][q];
            g00 += dot4(a0,b0); g01 += dot4(a0,b1);
            g10 += dot4(a1,b0); g11 += dot4(a1,b1);
        }
        g00 += __shfl_xor(g00, 1, 2);
        g01 += __shfl_xor(g01, 1, 2);
        g10 += __shfl_xor(g10, 1, 2);
        g11 += __shfl_xor(g11, 1, 2);
    }
    float sa0 = A.p3.S[ga]    * (1.f/256.f);
    float sa1 = A.p3.S[ga+16] * (1.f/256.f);
    float sb0 = A.p3.S[gb], sb1 = A.p3.S[gb+16];
    bar_wait(&g_bar1[gi]);

    // ---------------- P3c: mask + softmax + att@x ----------------
    if (qh == 0) {
        const float* Eb = Et + bm*1024;
        float e00 = ld_agent(&Eb[ga*32 + gb]);
        float e01 = ld_agent(&Eb[ga*32 + gb+16]);
        float e10 = ld_agent(&Eb[(ga+16)*32 + gb]);
        float e11 = ld_agent(&Eb[(ga+16)*32 + gb+16]);
        Bm.att[ga][gb]       = (g00 - sa0*sb0) > 0.f ? e00 : -1e12f;
        Bm.att[ga][gb+16]    = (g01 - sa0*sb1) > 0.f ? e01 : -1e12f;
        Bm.att[ga+16][gb]    = (g10 - sa1*sb0) > 0.f ? e10 : -1e12f;
        Bm.att[ga+16][gb+16] = (g11 - sa1*sb1) > 0.f ? e11 : -1e12f;
    }
    __syncthreads();
    {
        // 32 rows x 16 lanes, 2 floats per lane
        int r = t >> 4, q = t & 15;
        float2 lg = *((const float2*)&Bm.att[r][q*2]);
        float m = fmaxf(lg.x, lg.y);
        m = fmaxf(m, __shfl_xor(m,1,16));
        m = fmaxf(m, __shfl_xor(m,2,16));
        m = fmaxf(m, __shfl_xor(m,4,16));
        m = fmaxf(m, __shfl_xor(m,8,16));
        float2 p;
        p.x = __expf(lg.x-m); p.y = __expf(lg.y-m);
        float s = p.x + p.y;
        s += __shfl_xor(s,1,16);
        s += __shfl_xor(s,2,16);
        s += __shfl_xor(s,4,16);
        s += __shfl_xor(s,8,16);
        float inv = 1.f/s;
        p.x*=inv; p.y*=inv;
        *((float2*)&Bm.att[r][q*2]) = p;
    }
    __syncthreads();
    {
        int txl = t & 31, wy = t >> 5;   // 32 f4 cols x 16 row-groups
        int r0 = wy*2;
        float4 acc0={0,0,0,0}, acc1={0,0,0,0};
        #pragma unroll
        for (int kq = 0; kq < 8; ++kq) {
            float4 xa = A.p3.xs4[kq*4+0][hh*32 + txl];
            float4 xb = A.p3.xs4[kq*4+1][hh*32 + txl];
            float4 xc = A.p3.xs4[kq*4+2][hh*32 + txl];
            float4 xd = A.p3.xs4[kq*4+3][hh*32 + txl];
            float4 w0 = *((const float4*)&Bm.att[r0+0][kq*4]);
            float4 w1 = *((const float4*)&Bm.att[r0+1][kq*4]);
            fma4(acc0,w0.x,xa); fma4(acc0,w0.y,xb); fma4(acc0,w0.z,xc); fma4(acc0,w0.w,xd);
            fma4(acc1,w1.x,xa); fma4(acc1,w1.y,xb); fma4(acc1,w1.z,xc); fma4(acc1,w1.w,xd);
        }
        float4* out4 = (float4*)out;
        int base = bm*2048 + hh*32 + txl;
        out4[base + (r0+0)*64] = acc0;
        out4[base + (r0+1)*64] = acc1;
    }

    // ---------------- self-reset of group counters for next launch --------
    if (t == 0) {
        unsigned int old = __hip_atomic_fetch_add(&g_done[gi], 1u,
                              __ATOMIC_RELAXED, __HIP_MEMORY_SCOPE_AGENT);
        if (old == 15u) {
            __hip_atomic_store(&g_bar0[gi], 0u, __ATOMIC_RELAXED, __HIP_MEMORY_SCOPE_AGENT);
            __hip_atomic_store(&g_bar1[gi], 0u, __ATOMIC_RELAXED, __HIP_MEMORY_SCOPE_AGENT);
            __hip_atomic_store(&g_done[gi], 0u, __ATOMIC_RELAXED, __HIP_MEMORY_SCOPE_AGENT);
        }
    }
}

extern "C" void kernel_launch(void* const* d_in, const int* in_sizes, int n_in,
                              void* d_out, int out_size, void* d_ws, size_t ws_size,
                              hipStream_t stream) {
    const float* x  = (const float*)d_in[0];
    const float* W1 = (const float*)d_in[1];
    const float* W2 = (const float*)d_in[2];
    float* out = (float*)d_out;
    float* ws  = (float*)d_ws;

    float* Ht = ws;            // 49152 floats
    float* Et = ws + 49152;    // 98304 floats

    fused<<<192, 512, 0, stream>>>(x, W1, W2, out, Ht, Et);
}